// Round 2
// baseline (918.887 us; speedup 1.0000x reference)
//
#include <hip/hip_runtime.h>
#include <cfloat>
#include <climits>
#include <cstdint>
#include <cstddef>

#define ZD    128
#define NQ    256      // 4*64 queries
#define NB    4
#define NT    64
#define KK    100
#define CAP   2048
#define NSAMP 4096
#define RANK  24
#define MARGIN 6.0f    // rigorous bf16-filter slack: |d_exact - d_bf16| <~ 1.8

typedef __attribute__((ext_vector_type(8))) short  short8;   // 8 bf16 (4 VGPRs)
typedef __attribute__((ext_vector_type(4))) float  floatx4;  // mfma acc

__device__ inline unsigned short f2bf(float f) {   // RNE fp32 -> bf16
  unsigned u = __builtin_bit_cast(unsigned, f);
  unsigned r = u + 0x7fffu + ((u >> 16) & 1u);
  return (unsigned short)(r >> 16);
}

// ---------------------------------------------------------------- k0: norms + zero counters
__global__ __launch_bounds__(256) void k0_norms(
    const float* __restrict__ Q, const float* __restrict__ T, int M,
    float* __restrict__ qn, float* __restrict__ tn, int* __restrict__ cnt) {
  int gid = blockIdx.x * 256 + threadIdx.x;
  if (gid < M) {
    const float* r = T + (size_t)gid * ZD;
    float s = 0.f;
    #pragma unroll
    for (int z4 = 0; z4 < 32; ++z4) {
      float4 v = *(const float4*)&r[z4 * 4];
      s = fmaf(v.x, v.x, s); s = fmaf(v.y, v.y, s);
      s = fmaf(v.z, v.z, s); s = fmaf(v.w, v.w, s);
    }
    tn[gid] = s;
  } else if (gid < M + NQ) {
    int q = gid - M;
    const float* r = Q + (size_t)q * ZD;
    float s = 0.f;
    #pragma unroll
    for (int z4 = 0; z4 < 32; ++z4) {
      float4 v = *(const float4*)&r[z4 * 4];
      s = fmaf(v.x, v.x, s); s = fmaf(v.y, v.y, s);
      s = fmaf(v.z, v.z, s); s = fmaf(v.w, v.w, s);
    }
    qn[q] = s;
  } else if (gid < M + 2 * NQ) {
    cnt[gid - M - NQ] = 0;
  }
}

// ---------------------------------------------------------------- k1: per-query threshold from sample
__global__ __launch_bounds__(256) void k1_thresh(
    const float* __restrict__ Q, const float* __restrict__ T, int M,
    const float* __restrict__ qn, const float* __restrict__ tn,
    float* __restrict__ thr) {
  __shared__ float qv[ZD];
  __shared__ float sd[NSAMP];
  __shared__ float red[256];
  __shared__ int   hist[256];
  const int q = blockIdx.x, tid = threadIdx.x;
  for (int z = tid; z < ZD; z += 256) qv[z] = Q[(size_t)q * ZD + z];
  __syncthreads();
  const float qnv = qn[q];
  for (int s = tid; s < NSAMP; s += 256) {
    const float* r = T + (size_t)s * ZD;
    float dot = 0.f;
    #pragma unroll 8
    for (int z = 0; z < ZD; ++z) dot = fmaf(qv[z], r[z], dot);
    sd[s] = fmaf(-2.0f, dot, qnv + tn[s]);
  }
  __syncthreads();
  float lm = FLT_MAX;
  for (int s = tid; s < NSAMP; s += 256) lm = fminf(lm, sd[s]);
  red[tid] = lm;
  __syncthreads();
  for (int o = 128; o > 0; o >>= 1) {
    if (tid < o) red[tid] = fminf(red[tid], red[tid + o]);
    __syncthreads();
  }
  const float dmin = red[0];
  hist[tid] = 0;
  __syncthreads();
  for (int s = tid; s < NSAMP; s += 256) {
    int b = (int)((sd[s] - dmin) * 3.2f);     // bin width 0.3125 over [dmin, dmin+80]
    b = b < 0 ? 0 : (b > 255 ? 255 : b);
    atomicAdd(&hist[b], 1);
  }
  __syncthreads();
  if (tid == 0) {
    int cum = 0; float Tq = dmin + 80.0f;
    for (int b = 0; b < 256; ++b) {
      cum += hist[b];
      if (cum >= RANK) { Tq = dmin + (float)(b + 1) * 0.3125f; break; }
    }
    thr[q] = Tq;
  }
}

// ---------------------------------------------------------------- k2: bf16 MFMA approximate filter
// Tile: 64 targets x 128 queries, K=128. grid = (ceil(M/64), 2).
// LDS rows padded to 136 bf16 (272 B) so frag reads stay 16B-aligned.
#define TROWS 64
#define QROWS 128
#define LPAD  136
__global__ __launch_bounds__(256) void k2_mfma(
    const float* __restrict__ Q, const float* __restrict__ T, int M,
    const float* __restrict__ qn, const float* __restrict__ tn,
    const float* __restrict__ thr, int* __restrict__ cnt,
    int* __restrict__ cand_i) {
  __shared__ short Ts[TROWS * LPAD];
  __shared__ short Qs[QROWS * LPAD];
  const int tid = threadIdx.x;
  const int m0 = blockIdx.x * TROWS;
  const int qbase = blockIdx.y * QROWS;

  // stage T tile: 64 rows x 32 float4 chunks
  #pragma unroll
  for (int it = 0; it < 8; ++it) {
    int li = tid + it * 256;
    int row = li >> 5, z4 = li & 31;
    int m = m0 + row;
    float4 v = make_float4(0.f, 0.f, 0.f, 0.f);
    if (m < M) v = *(const float4*)&T[(size_t)m * ZD + z4 * 4];
    unsigned lo = (unsigned)f2bf(v.x) | ((unsigned)f2bf(v.y) << 16);
    unsigned hi = (unsigned)f2bf(v.z) | ((unsigned)f2bf(v.w) << 16);
    *(uint2*)&Ts[row * LPAD + z4 * 4] = make_uint2(lo, hi);
  }
  // stage Q tile: 128 rows x 32 chunks
  #pragma unroll
  for (int it = 0; it < 16; ++it) {
    int li = tid + it * 256;
    int row = li >> 5, z4 = li & 31;
    float4 v = *(const float4*)&Q[(size_t)(qbase + row) * ZD + z4 * 4];
    unsigned lo = (unsigned)f2bf(v.x) | ((unsigned)f2bf(v.y) << 16);
    unsigned hi = (unsigned)f2bf(v.z) | ((unsigned)f2bf(v.w) << 16);
    *(uint2*)&Qs[row * LPAD + z4 * 4] = make_uint2(lo, hi);
  }
  __syncthreads();

  const int wave = tid >> 6;       // 0..3 -> 16 targets each
  const int lane = tid & 63;
  const int quad = lane >> 4;      // 0..3
  const int n16  = lane & 15;

  floatx4 acc[8];
  #pragma unroll
  for (int qt = 0; qt < 8; ++qt) acc[qt] = (floatx4)0.f;

  #pragma unroll
  for (int ks = 0; ks < 4; ++ks) {
    // A frag: A[m=n16][k=quad*8+j], targets
    short8 a = *(const short8*)&Ts[(wave * 16 + n16) * LPAD + ks * 32 + quad * 8];
    #pragma unroll
    for (int qt = 0; qt < 8; ++qt) {
      // B frag of B=Q^T: B[k=quad*8+j][n=n16] == Q[n16][k...]
      short8 b = *(const short8*)&Qs[(qt * 16 + n16) * LPAD + ks * 32 + quad * 8];
      acc[qt] = __builtin_amdgcn_mfma_f32_16x16x32_bf16(a, b, acc[qt], 0, 0, 0);
    }
  }

  // epilogue: D row = quad*4+reg (target), col = n16 (query)
  const int mbase = m0 + wave * 16 + quad * 4;
  float4 tnv = make_float4(0.f, 0.f, 0.f, 0.f);
  if (mbase + 3 < M) tnv = *(const float4*)&tn[mbase];
  else {
    if (mbase + 0 < M) tnv.x = tn[mbase + 0];
    if (mbase + 1 < M) tnv.y = tn[mbase + 1];
    if (mbase + 2 < M) tnv.z = tn[mbase + 2];
    if (mbase + 3 < M) tnv.w = tn[mbase + 3];
  }
  #pragma unroll
  for (int qt = 0; qt < 8; ++qt) {
    const int q = qbase + qt * 16 + n16;
    const float base = qn[q];
    const float Tq = thr[q] + MARGIN;
    const float tns[4] = {tnv.x, tnv.y, tnv.z, tnv.w};
    #pragma unroll
    for (int r = 0; r < 4; ++r) {
      const int m = mbase + r;
      float dap = fmaf(-2.0f, acc[qt][r], base + tns[r]);
      if (m < M && dap < Tq) {
        int pos = atomicAdd(&cnt[q], 1);
        if (pos < CAP) cand_i[(size_t)q * CAP + pos] = m;
      }
    }
  }
}

// ---------------------------------------------------------------- k3: exact rescore + top-K + softmax
__global__ __launch_bounds__(256) void k3_select(
    const float* __restrict__ Q, const float* __restrict__ T, int M,
    const float* __restrict__ qn, const float* __restrict__ tn,
    const int* __restrict__ cnt, const int* __restrict__ cand_i,
    int* __restrict__ topi, float* __restrict__ emit) {
  __shared__ float sd[CAP];
  __shared__ int   si[CAP];
  __shared__ float qv[ZD];
  __shared__ float cd[256];
  __shared__ float ebuf[KK];
  __shared__ float ssum;
  const int q = blockIdx.x, tid = threadIdx.x;
  const int raw = cnt[q];
  const bool valid = (raw >= KK && raw <= CAP);
  for (int z = tid; z < ZD; z += 256) qv[z] = Q[(size_t)q * ZD + z];
  const float qnv = qn[q];
  if (valid) {
    for (int i = tid; i < CAP; i += 256)
      si[i] = (i < raw) ? cand_i[(size_t)q * CAP + i] : INT_MAX;
    __syncthreads();
    // exact fp32 rescore (same sequential fmaf chain as fallback/k1)
    for (int i = tid; i < CAP; i += 256) {
      if (i < raw) {
        const float* r = T + (size_t)si[i] * ZD;
        float dot = 0.f;
        #pragma unroll 4
        for (int z4 = 0; z4 < 32; ++z4) {
          float4 v = *(const float4*)&r[z4 * 4];
          dot = fmaf(qv[z4 * 4 + 0], v.x, dot);
          dot = fmaf(qv[z4 * 4 + 1], v.y, dot);
          dot = fmaf(qv[z4 * 4 + 2], v.z, dot);
          dot = fmaf(qv[z4 * 4 + 3], v.w, dot);
        }
        sd[i] = fmaf(-2.0f, dot, qnv + tn[si[i]]);
      } else {
        sd[i] = FLT_MAX;
      }
    }
    __syncthreads();
  } else {
    // brute-force exact fallback (essentially never taken; correctness net)
    if (tid == 0) for (int k = 0; k < KK; ++k) { sd[k] = FLT_MAX; si[k] = INT_MAX; }
    __syncthreads();
    for (int base = 0; base < M; base += 256) {
      int m = base + tid; float d = FLT_MAX;
      if (m < M) {
        const float* r = T + (size_t)m * ZD;
        float dot = 0.f;
        for (int z = 0; z < ZD; ++z) dot = fmaf(qv[z], r[z], dot);
        d = fmaf(-2.0f, dot, qnv + tn[m]);
      }
      cd[tid] = d;
      __syncthreads();
      if (tid == 0) {
        for (int e = 0; e < 256; ++e) {
          float dd = cd[e]; int mm = base + e;
          if (dd < sd[KK - 1] || (dd == sd[KK - 1] && mm < si[KK - 1])) {
            int pos = KK - 1;
            while (pos > 0 && (sd[pos - 1] > dd || (sd[pos - 1] == dd && si[pos - 1] > mm))) {
              sd[pos] = sd[pos - 1]; si[pos] = si[pos - 1]; --pos;
            }
            sd[pos] = dd; si[pos] = mm;
          }
        }
      }
      __syncthreads();
    }
    for (int i = KK + tid; i < CAP; i += 256) { sd[i] = FLT_MAX; si[i] = INT_MAX; }
    __syncthreads();
  }
  // bitonic sort ascending by (d, idx) — matches lax.top_k stable tie-break
  for (int k = 2; k <= CAP; k <<= 1) {
    for (int j = k >> 1; j > 0; j >>= 1) {
      for (int t = tid; t < CAP; t += 256) {
        int x = t ^ j;
        if (x > t) {
          bool asc = ((t & k) == 0);
          float d1 = sd[t], d2 = sd[x];
          int   i1 = si[t], i2 = si[x];
          bool g = (d1 > d2) || (d1 == d2 && i1 > i2);
          if (g == asc) { sd[t] = d2; sd[x] = d1; si[t] = i2; si[x] = i1; }
        }
      }
      __syncthreads();
    }
  }
  if (tid == 0) {
    float d0 = sd[0], sum = 0.f;
    for (int k = 0; k < KK; ++k) {
      float e = expf(d0 - sd[k]);   // softmax(-d): exp(d0 - d_k)
      ebuf[k] = e; sum += e;
    }
    ssum = sum;
  }
  __syncthreads();
  if (tid < KK) {
    emit[(size_t)q * KK + tid] = ebuf[tid] / ssum;
    topi[(size_t)q * KK + tid] = si[tid];
  }
}

// ---------------------------------------------------------------- k4: transition matrices exp(-d)
__global__ __launch_bounds__(256) void k4_trans(
    const float* __restrict__ T, const int* __restrict__ topi,
    float* __restrict__ trans) {
  const int bt = blockIdx.x;                 // 0..251
  const int b = bt / (NT - 1), t = bt % (NT - 1);
  const int* iA = topi + (size_t)(b * NT + t) * KK;
  const int* iB = topi + (size_t)(b * NT + t + 1) * KK;
  __shared__ float As[KK * 132];
  __shared__ float Bs[20 * 132];
  __shared__ float an[KK];
  __shared__ float bn[20];
  const int tid = threadIdx.x;
  for (int li = tid; li < KK * 32; li += 256) {
    int row = li >> 5, z4 = li & 31;
    float4 v = *(const float4*)&T[(size_t)iA[row] * ZD + z4 * 4];
    *(float4*)&As[row * 132 + z4 * 4] = v;
  }
  __syncthreads();
  if (tid < KK) {
    float s = 0.f;
    for (int z = 0; z < ZD; ++z) s = fmaf(As[tid * 132 + z], As[tid * 132 + z], s);
    an[tid] = s;
  }
  for (int c = 0; c < 5; ++c) {
    __syncthreads();
    for (int li = tid; li < 20 * 32; li += 256) {
      int row = li >> 5, z4 = li & 31;
      float4 v = *(const float4*)&T[(size_t)iB[c * 20 + row] * ZD + z4 * 4];
      *(float4*)&Bs[row * 132 + z4 * 4] = v;
    }
    __syncthreads();
    if (tid < 20) {
      float s = 0.f;
      for (int z = 0; z < ZD; ++z) s = fmaf(Bs[tid * 132 + z], Bs[tid * 132 + z], s);
      bn[tid] = s;
    }
    __syncthreads();
    if (tid < 125) {
      const int i0 = (tid / 5) * 4, j0 = (tid % 5) * 4;
      float acc[16];
      #pragma unroll
      for (int x = 0; x < 16; ++x) acc[x] = 0.f;
      for (int z4 = 0; z4 < 32; ++z4) {
        float4 a[4], bb[4];
        #pragma unroll
        for (int r = 0; r < 4; ++r) a[r] = *(const float4*)&As[(i0 + r) * 132 + z4 * 4];
        #pragma unroll
        for (int s = 0; s < 4; ++s) bb[s] = *(const float4*)&Bs[(j0 + s) * 132 + z4 * 4];
        #pragma unroll
        for (int r = 0; r < 4; ++r) {
          #pragma unroll
          for (int s = 0; s < 4; ++s) {
            acc[r * 4 + s] = fmaf(a[r].x, bb[s].x, acc[r * 4 + s]);
            acc[r * 4 + s] = fmaf(a[r].y, bb[s].y, acc[r * 4 + s]);
            acc[r * 4 + s] = fmaf(a[r].z, bb[s].z, acc[r * 4 + s]);
            acc[r * 4 + s] = fmaf(a[r].w, bb[s].w, acc[r * 4 + s]);
          }
        }
      }
      float* trow = trans + (size_t)bt * KK * KK;
      #pragma unroll
      for (int r = 0; r < 4; ++r)
        for (int s = 0; s < 4; ++s) {
          float d = fmaf(-2.0f, acc[r * 4 + s], an[i0 + r] + bn[j0 + s]);
          trow[(i0 + r) * KK + c * 20 + j0 + s] = expf(-d);
        }
    }
  }
}

// ---------------------------------------------------------------- k5: Viterbi + backtrack + gather
__global__ __launch_bounds__(256) void k5_viterbi(
    const float* __restrict__ T, const int* __restrict__ topi,
    const float* __restrict__ emit, const float* __restrict__ trans,
    int* __restrict__ backp, float* __restrict__ out) {
  const int b = blockIdx.x, tid = threadIdx.x;
  __shared__ float trS[KK * KK];
  __shared__ float v[KK], vn[KK];
  __shared__ float pb[200];
  __shared__ int   pi[200];
  __shared__ int   path[NT];
  __shared__ float maxsh;
  __shared__ int   zflag;
  if (tid < KK) v[tid] = emit[(size_t)(b * NT) * KK + tid];
  if (tid == 0) zflag = 0;
  __syncthreads();
  for (int t = 1; t < NT; ++t) {
    const int zf = zflag;     // uniform across block
    if (zf == 0) {
      const float* trg = trans + (size_t)(b * (NT - 1) + (t - 1)) * KK * KK;
      for (int li = tid; li < (KK * KK) / 4; li += 256)
        *(float4*)&trS[li * 4] = *(const float4*)&trg[li * 4];
      __syncthreads();
      if (tid < 200) {
        const int j = tid % 100, half = tid / 100;
        const int ia = half * 50, ibnd = ia + 50;
        float best = -FLT_MAX; int bi = ia;
        for (int i = ia; i < ibnd; ++i) {
          float s = v[i] * trS[i * KK + j];
          if (s > best) { best = s; bi = i; }     // strict > == argmax-first
        }
        pb[tid] = best; pi[tid] = bi;
      }
      __syncthreads();
      if (tid < KK) {
        float b0 = pb[tid], b1 = pb[100 + tid];
        int   i0 = pi[tid], i1 = pi[100 + tid];
        float best = b0; int bi = i0;
        if (b1 > b0) { best = b1; bi = i1; }      // half-1 indices all larger
        vn[tid] = best * emit[(size_t)(b * NT + t) * KK + tid];
        backp[(size_t)(b * (NT - 1) + (t - 1)) * KK + tid] = bi;
      }
      __syncthreads();
      if (tid == 0) {
        float m = vn[0];
        for (int j = 1; j < KK; ++j) m = fmaxf(m, vn[j]);
        maxsh = m;
        if (m == 0.0f) zflag = 1;   // exact shortcut: all-zero v is absorbing
      }
      __syncthreads();
      if (tid < KK) v[tid] = vn[tid] / fmaxf(maxsh, 1e-30f);
    } else {
      if (tid < KK) backp[(size_t)(b * (NT - 1) + (t - 1)) * KK + tid] = 0;
    }
    __syncthreads();
  }
  if (tid == 0) {
    float best = -FLT_MAX; int last = 0;
    for (int j = 0; j < KK; ++j) if (v[j] > best) { best = v[j]; last = j; }
    path[NT - 1] = last;
    for (int tt = NT - 2; tt >= 0; --tt)
      path[tt] = backp[(size_t)(b * (NT - 1) + tt) * KK + path[tt + 1]];
  }
  __syncthreads();
  for (int li = tid; li < NT * ZD; li += 256) {
    int t = li >> 7, z = li & 127;
    out[(size_t)(b * NT + t) * ZD + z] =
        T[(size_t)topi[(size_t)(b * NT + t) * KK + path[t]] * ZD + z];
  }
}

// ---------------------------------------------------------------- host
extern "C" void kernel_launch(void* const* d_in, const int* in_sizes, int n_in,
                              void* d_out, int out_size, void* d_ws, size_t ws_size,
                              hipStream_t stream) {
  const float* Q = (const float*)d_in[0];     // (4,64,128) fp32
  const float* T = (const float*)d_in[1];     // (100000,128) fp32
  float* out = (float*)d_out;                 // (4,64,128) fp32
  const int M = in_sizes[1] / ZD;

  char* p = (char*)d_ws;
  auto alloc = [&](size_t bytes) -> char* {
    char* r = p; p += (bytes + 511) & ~(size_t)511; return r;
  };
  float* qn     = (float*)alloc((size_t)NQ * 4);
  float* tn     = (float*)alloc((size_t)M * 4);
  float* thr    = (float*)alloc((size_t)NQ * 4);
  int*   cnt    = (int*)  alloc((size_t)NQ * 4);
  int*   cand_i = (int*)  alloc((size_t)NQ * CAP * 4);
  int*   topi   = (int*)  alloc((size_t)NQ * KK * 4);
  float* emit   = (float*)alloc((size_t)NQ * KK * 4);
  float* trans  = (float*)alloc((size_t)NB * (NT - 1) * KK * KK * 4);
  int*   backp  = (int*)  alloc((size_t)NB * (NT - 1) * KK * 4);

  const int g0 = (M + 2 * NQ + 255) / 256;
  k0_norms<<<g0, 256, 0, stream>>>(Q, T, M, qn, tn, cnt);
  k1_thresh<<<NQ, 256, 0, stream>>>(Q, T, M, qn, tn, thr);
  dim3 g2((M + TROWS - 1) / TROWS, NQ / QROWS);
  k2_mfma<<<g2, 256, 0, stream>>>(Q, T, M, qn, tn, thr, cnt, cand_i);
  k3_select<<<NQ, 256, 0, stream>>>(Q, T, M, qn, tn, cnt, cand_i, topi, emit);
  k4_trans<<<NB * (NT - 1), 256, 0, stream>>>(T, topi, trans);
  k5_viterbi<<<NB, 256, 0, stream>>>(T, topi, emit, trans, backp, out);
}

// Round 3
// 410.424 us; speedup vs baseline: 2.2389x; 2.2389x over previous
//
#include <hip/hip_runtime.h>
#include <cfloat>
#include <climits>
#include <cstdint>
#include <cstddef>

#define ZD    128
#define NQ    256      // 4*64 queries
#define NB    4
#define NT    64
#define KK    100
#define CAP   2048
#define NSAMP 4096
#define RANK  24
#define EPS   3.0f     // rigorous |d_bf16 - d_exact| bound (analysis: <= ~2.2)
#define SLABS 256
#define BKT   24       // per-(q,slab) bucket capacity; E[hits] ~ 3.3, Poisson tail ~1e-14
#define TROWS 64
#define QROWS 128
#define LPAD  136      // bf16 row stride (272 B), keeps 16B alignment

typedef __attribute__((ext_vector_type(8))) short  short8;   // 8 bf16 (4 VGPRs)
typedef __attribute__((ext_vector_type(4))) float  floatx4;  // mfma acc

__device__ inline unsigned short f2bf(float f) {   // RNE fp32 -> bf16
  unsigned u = __builtin_bit_cast(unsigned, f);
  unsigned r = u + 0x7fffu + ((u >> 16) & 1u);
  return (unsigned short)(r >> 16);
}

// ---------------------------------------------------------------- k0: norms
__global__ __launch_bounds__(256) void k0_norms(
    const float* __restrict__ Q, const float* __restrict__ T, int M,
    float* __restrict__ qn, float* __restrict__ tn) {
  int gid = blockIdx.x * 256 + threadIdx.x;
  if (gid < M) {
    const float* r = T + (size_t)gid * ZD;
    float s = 0.f;
    #pragma unroll
    for (int z4 = 0; z4 < 32; ++z4) {
      float4 v = *(const float4*)&r[z4 * 4];
      s = fmaf(v.x, v.x, s); s = fmaf(v.y, v.y, s);
      s = fmaf(v.z, v.z, s); s = fmaf(v.w, v.w, s);
    }
    tn[gid] = s;
  } else if (gid < M + NQ) {
    int q = gid - M;
    const float* r = Q + (size_t)q * ZD;
    float s = 0.f;
    #pragma unroll
    for (int z4 = 0; z4 < 32; ++z4) {
      float4 v = *(const float4*)&r[z4 * 4];
      s = fmaf(v.x, v.x, s); s = fmaf(v.y, v.y, s);
      s = fmaf(v.z, v.z, s); s = fmaf(v.w, v.w, s);
    }
    qn[q] = s;
  }
}

// ---------------------------------------------------------------- k1: per-query threshold from sample
__global__ __launch_bounds__(256) void k1_thresh(
    const float* __restrict__ Q, const float* __restrict__ T, int M,
    const float* __restrict__ qn, const float* __restrict__ tn,
    float* __restrict__ thr) {
  __shared__ float qv[ZD];
  __shared__ float sd[NSAMP];
  __shared__ float red[256];
  __shared__ int   hist[256];
  const int q = blockIdx.x, tid = threadIdx.x;
  for (int z = tid; z < ZD; z += 256) qv[z] = Q[(size_t)q * ZD + z];
  __syncthreads();
  const float qnv = qn[q];
  for (int s = tid; s < NSAMP; s += 256) {
    const float* r = T + (size_t)s * ZD;
    float dot = 0.f;
    #pragma unroll 8
    for (int z = 0; z < ZD; ++z) dot = fmaf(qv[z], r[z], dot);
    sd[s] = fmaf(-2.0f, dot, qnv + tn[s]);
  }
  __syncthreads();
  float lm = FLT_MAX;
  for (int s = tid; s < NSAMP; s += 256) lm = fminf(lm, sd[s]);
  red[tid] = lm;
  __syncthreads();
  for (int o = 128; o > 0; o >>= 1) {
    if (tid < o) red[tid] = fminf(red[tid], red[tid + o]);
    __syncthreads();
  }
  const float dmin = red[0];
  hist[tid] = 0;
  __syncthreads();
  for (int s = tid; s < NSAMP; s += 256) {
    int b = (int)((sd[s] - dmin) * 3.2f);     // bin width 0.3125 over [dmin, dmin+80]
    b = b < 0 ? 0 : (b > 255 ? 255 : b);
    atomicAdd(&hist[b], 1);
  }
  __syncthreads();
  if (tid == 0) {
    int cum = 0; float Tq = dmin + 80.0f;
    for (int b = 0; b < 256; ++b) {
      cum += hist[b];
      if (cum >= RANK) { Tq = dmin + (float)(b + 1) * 0.3125f; break; }
    }
    thr[q] = Tq;
  }
}

// ---------------------------------------------------------------- k2: bf16 MFMA filter, slab-bucketed,
// ZERO global atomics. Block (slab, yhalf) owns targets [slab*slabn, ...) for 128 queries.
__global__ __launch_bounds__(256) void k2_mfma(
    const float* __restrict__ Q, const float* __restrict__ T, int M, int slabn,
    const float* __restrict__ qn, const float* __restrict__ tn,
    const float* __restrict__ thr,
    int* __restrict__ cnt2, int* __restrict__ sure2, int* __restrict__ cand) {
  __shared__ short Ts[TROWS * LPAD];
  __shared__ short Qs[QROWS * LPAD];
  __shared__ int   lcnt[QROWS];
  __shared__ int   lsure[QROWS];
  __shared__ int   lent[QROWS * BKT];
  const int tid = threadIdx.x;
  const int slab = blockIdx.x;
  const int qbase = blockIdx.y * QROWS;
  const int sbeg = slab * slabn;
  const int send = min(sbeg + slabn, M);

  // stage Q tile once (128 rows x 32 float4 chunks), fp32 -> bf16
  #pragma unroll
  for (int it = 0; it < 16; ++it) {
    int li = tid + it * 256;
    int row = li >> 5, z4 = li & 31;
    float4 v = *(const float4*)&Q[(size_t)(qbase + row) * ZD + z4 * 4];
    unsigned lo = (unsigned)f2bf(v.x) | ((unsigned)f2bf(v.y) << 16);
    unsigned hi = (unsigned)f2bf(v.z) | ((unsigned)f2bf(v.w) << 16);
    *(uint2*)&Qs[row * LPAD + z4 * 4] = make_uint2(lo, hi);
  }
  if (tid < QROWS) { lcnt[tid] = 0; lsure[tid] = 0; }

  const int wave = tid >> 6;       // 0..3 -> 16 targets each
  const int lane = tid & 63;
  const int quad = lane >> 4;      // 0..3
  const int n16  = lane & 15;

  for (int m0 = sbeg; m0 < send; m0 += TROWS) {   // uniform trip count per block
    __syncthreads();   // publish Qs (1st iter) / protect Ts from prev tile's readers
    // stage T tile (64 rows x 32 chunks), zero-pad beyond slab end
    #pragma unroll
    for (int it = 0; it < 8; ++it) {
      int li = tid + it * 256;
      int row = li >> 5, z4 = li & 31;
      int m = m0 + row;
      float4 v = make_float4(0.f, 0.f, 0.f, 0.f);
      if (m < send) v = *(const float4*)&T[(size_t)m * ZD + z4 * 4];
      unsigned lo = (unsigned)f2bf(v.x) | ((unsigned)f2bf(v.y) << 16);
      unsigned hi = (unsigned)f2bf(v.z) | ((unsigned)f2bf(v.w) << 16);
      *(uint2*)&Ts[row * LPAD + z4 * 4] = make_uint2(lo, hi);
    }
    __syncthreads();

    floatx4 acc[8];
    #pragma unroll
    for (int qt = 0; qt < 8; ++qt) acc[qt] = (floatx4)0.f;
    #pragma unroll
    for (int ks = 0; ks < 4; ++ks) {
      short8 a = *(const short8*)&Ts[(wave * 16 + n16) * LPAD + ks * 32 + quad * 8];
      #pragma unroll
      for (int qt = 0; qt < 8; ++qt) {
        short8 b = *(const short8*)&Qs[(qt * 16 + n16) * LPAD + ks * 32 + quad * 8];
        acc[qt] = __builtin_amdgcn_mfma_f32_16x16x32_bf16(a, b, acc[qt], 0, 0, 0);
      }
    }

    // epilogue: D row = quad*4+reg (target), col = n16 (query)
    const int mbase = m0 + wave * 16 + quad * 4;
    float4 tnv = make_float4(0.f, 0.f, 0.f, 0.f);
    if (mbase + 3 < M) tnv = *(const float4*)&tn[mbase];
    else {
      if (mbase + 0 < M) tnv.x = tn[mbase + 0];
      if (mbase + 1 < M) tnv.y = tn[mbase + 1];
      if (mbase + 2 < M) tnv.z = tn[mbase + 2];
    }
    const float tns[4] = {tnv.x, tnv.y, tnv.z, tnv.w};
    #pragma unroll
    for (int qt = 0; qt < 8; ++qt) {
      const int ql = qt * 16 + n16;
      const int q = qbase + ql;
      const float base = qn[q];
      const float Tq = thr[q];
      #pragma unroll
      for (int r = 0; r < 4; ++r) {
        const int m = mbase + r;
        float dap = fmaf(-2.0f, acc[qt][r], base + tns[r]);
        if (m < send && dap < Tq + EPS) {
          int pos = atomicAdd(&lcnt[ql], 1);          // LDS atomic — local, cheap
          if (pos < BKT) lent[ql * BKT + pos] = m;
          if (dap < Tq - EPS) atomicAdd(&lsure[ql], 1);
        }
      }
    }
  }
  __syncthreads();
  // coalesced writeout — unique (q,slab) owner, no global atomics
  if (tid < QROWS) {
    cnt2 [(size_t)(qbase + tid) * SLABS + slab] = lcnt[tid];
    sure2[(size_t)(qbase + tid) * SLABS + slab] = lsure[tid];
  }
  for (int li = tid; li < QROWS * BKT; li += 256) {
    int ql = li / BKT, j = li % BKT;
    int c = lcnt[ql]; if (c > BKT) c = BKT;
    if (j < c)
      cand[((size_t)(qbase + ql) * SLABS + slab) * BKT + j] = lent[li];
  }
}

// ---------------------------------------------------------------- k3: gather + exact rescore + top-K + softmax
__global__ __launch_bounds__(256) void k3_select(
    const float* __restrict__ Q, const float* __restrict__ T, int M,
    const float* __restrict__ qn, const float* __restrict__ tn,
    const int* __restrict__ cnt2, const int* __restrict__ sure2,
    const int* __restrict__ cand,
    int* __restrict__ topi, float* __restrict__ emit) {
  __shared__ float sd[CAP];
  __shared__ int   si[CAP];
  __shared__ float qv[ZD];
  __shared__ float cd[256];
  __shared__ float ebuf[KK];
  __shared__ float ssum;
  __shared__ int   sscan[256];
  __shared__ int   ssure, sovf;
  const int q = blockIdx.x, tid = threadIdx.x;

  // per-slab counts for this query
  int c = cnt2[(size_t)q * SLABS + tid];
  int su = sure2[(size_t)q * SLABS + tid];
  if (tid == 0) { ssure = 0; sovf = 0; }
  for (int i = tid; i < CAP; i += 256) { sd[i] = FLT_MAX; si[i] = INT_MAX; }
  __syncthreads();
  atomicAdd(&ssure, su);
  if (c > BKT) atomicOr(&sovf, 1);
  // inclusive Hillis-Steele scan of c over 256 slabs
  int val = c;
  sscan[tid] = val;
  __syncthreads();
  for (int o = 1; o < 256; o <<= 1) {
    int add = (tid >= o) ? sscan[tid - o] : 0;
    __syncthreads();
    val += add;
    sscan[tid] = val;
    __syncthreads();
  }
  const int total = sscan[255];
  const bool valid = (sovf == 0) && (ssure >= KK) && (total <= CAP);
  for (int z = tid; z < ZD; z += 256) qv[z] = Q[(size_t)q * ZD + z];
  const float qnv = qn[q];

  if (valid) {
    // gather: thread tid copies its slab's c entries to si[off..off+c)
    const int off = val - c;
    for (int j = 0; j < c; ++j)
      si[off + j] = cand[((size_t)q * SLABS + tid) * BKT + j];
    __syncthreads();
    // exact fp32 rescore (same sequential fmaf chain as fallback/k1)
    for (int i = tid; i < CAP; i += 256) {
      if (i < total) {
        const float* r = T + (size_t)si[i] * ZD;
        float dot = 0.f;
        #pragma unroll 4
        for (int z4 = 0; z4 < 32; ++z4) {
          float4 v = *(const float4*)&r[z4 * 4];
          dot = fmaf(qv[z4 * 4 + 0], v.x, dot);
          dot = fmaf(qv[z4 * 4 + 1], v.y, dot);
          dot = fmaf(qv[z4 * 4 + 2], v.z, dot);
          dot = fmaf(qv[z4 * 4 + 3], v.w, dot);
        }
        sd[i] = fmaf(-2.0f, dot, qnv + tn[si[i]]);
      }
    }
    __syncthreads();
  } else {
    // brute-force exact fallback (essentially never taken; correctness net)
    __syncthreads();
    if (tid == 0) for (int k = 0; k < KK; ++k) { sd[k] = FLT_MAX; si[k] = INT_MAX; }
    __syncthreads();
    for (int base = 0; base < M; base += 256) {
      int m = base + tid; float d = FLT_MAX;
      if (m < M) {
        const float* r = T + (size_t)m * ZD;
        float dot = 0.f;
        for (int z = 0; z < ZD; ++z) dot = fmaf(qv[z], r[z], dot);
        d = fmaf(-2.0f, dot, qnv + tn[m]);
      }
      cd[tid] = d;
      __syncthreads();
      if (tid == 0) {
        for (int e = 0; e < 256; ++e) {
          float dd = cd[e]; int mm = base + e;
          if (dd < sd[KK - 1] || (dd == sd[KK - 1] && mm < si[KK - 1])) {
            int pos = KK - 1;
            while (pos > 0 && (sd[pos - 1] > dd || (sd[pos - 1] == dd && si[pos - 1] > mm))) {
              sd[pos] = sd[pos - 1]; si[pos] = si[pos - 1]; --pos;
            }
            sd[pos] = dd; si[pos] = mm;
          }
        }
      }
      __syncthreads();
    }
    for (int i = KK + tid; i < CAP; i += 256) { sd[i] = FLT_MAX; si[i] = INT_MAX; }
    __syncthreads();
  }
  // bitonic sort ascending by (d, idx) — matches lax.top_k stable tie-break
  for (int k = 2; k <= CAP; k <<= 1) {
    for (int j = k >> 1; j > 0; j >>= 1) {
      for (int t = tid; t < CAP; t += 256) {
        int x = t ^ j;
        if (x > t) {
          bool asc = ((t & k) == 0);
          float d1 = sd[t], d2 = sd[x];
          int   i1 = si[t], i2 = si[x];
          bool g = (d1 > d2) || (d1 == d2 && i1 > i2);
          if (g == asc) { sd[t] = d2; sd[x] = d1; si[t] = i2; si[x] = i1; }
        }
      }
      __syncthreads();
    }
  }
  if (tid == 0) {
    float d0 = sd[0], sum = 0.f;
    for (int k = 0; k < KK; ++k) {
      float e = expf(d0 - sd[k]);   // softmax(-d): exp(d0 - d_k)
      ebuf[k] = e; sum += e;
    }
    ssum = sum;
  }
  __syncthreads();
  if (tid < KK) {
    emit[(size_t)q * KK + tid] = ebuf[tid] / ssum;
    topi[(size_t)q * KK + tid] = si[tid];
  }
}

// ---------------------------------------------------------------- k4: transition matrices exp(-d)
__global__ __launch_bounds__(256) void k4_trans(
    const float* __restrict__ T, const int* __restrict__ topi,
    float* __restrict__ trans) {
  const int bt = blockIdx.x;                 // 0..251
  const int b = bt / (NT - 1), t = bt % (NT - 1);
  const int* iA = topi + (size_t)(b * NT + t) * KK;
  const int* iB = topi + (size_t)(b * NT + t + 1) * KK;
  __shared__ float As[KK * 132];
  __shared__ float Bs[20 * 132];
  __shared__ float an[KK];
  __shared__ float bn[20];
  const int tid = threadIdx.x;
  for (int li = tid; li < KK * 32; li += 256) {
    int row = li >> 5, z4 = li & 31;
    float4 v = *(const float4*)&T[(size_t)iA[row] * ZD + z4 * 4];
    *(float4*)&As[row * 132 + z4 * 4] = v;
  }
  __syncthreads();
  if (tid < KK) {
    float s = 0.f;
    for (int z = 0; z < ZD; ++z) s = fmaf(As[tid * 132 + z], As[tid * 132 + z], s);
    an[tid] = s;
  }
  for (int c = 0; c < 5; ++c) {
    __syncthreads();
    for (int li = tid; li < 20 * 32; li += 256) {
      int row = li >> 5, z4 = li & 31;
      float4 v = *(const float4*)&T[(size_t)iB[c * 20 + row] * ZD + z4 * 4];
      *(float4*)&Bs[row * 132 + z4 * 4] = v;
    }
    __syncthreads();
    if (tid < 20) {
      float s = 0.f;
      for (int z = 0; z < ZD; ++z) s = fmaf(Bs[tid * 132 + z], Bs[tid * 132 + z], s);
      bn[tid] = s;
    }
    __syncthreads();
    if (tid < 125) {
      const int i0 = (tid / 5) * 4, j0 = (tid % 5) * 4;
      float acc[16];
      #pragma unroll
      for (int x = 0; x < 16; ++x) acc[x] = 0.f;
      for (int z4 = 0; z4 < 32; ++z4) {
        float4 a[4], bb[4];
        #pragma unroll
        for (int r = 0; r < 4; ++r) a[r] = *(const float4*)&As[(i0 + r) * 132 + z4 * 4];
        #pragma unroll
        for (int s = 0; s < 4; ++s) bb[s] = *(const float4*)&Bs[(j0 + s) * 132 + z4 * 4];
        #pragma unroll
        for (int r = 0; r < 4; ++r) {
          #pragma unroll
          for (int s = 0; s < 4; ++s) {
            acc[r * 4 + s] = fmaf(a[r].x, bb[s].x, acc[r * 4 + s]);
            acc[r * 4 + s] = fmaf(a[r].y, bb[s].y, acc[r * 4 + s]);
            acc[r * 4 + s] = fmaf(a[r].z, bb[s].z, acc[r * 4 + s]);
            acc[r * 4 + s] = fmaf(a[r].w, bb[s].w, acc[r * 4 + s]);
          }
        }
      }
      float* trow = trans + (size_t)bt * KK * KK;
      #pragma unroll
      for (int r = 0; r < 4; ++r)
        for (int s = 0; s < 4; ++s) {
          float d = fmaf(-2.0f, acc[r * 4 + s], an[i0 + r] + bn[j0 + s]);
          trow[(i0 + r) * KK + c * 20 + j0 + s] = expf(-d);
        }
    }
  }
}

// ---------------------------------------------------------------- k5: Viterbi + backtrack + gather
__global__ __launch_bounds__(256) void k5_viterbi(
    const float* __restrict__ T, const int* __restrict__ topi,
    const float* __restrict__ emit, const float* __restrict__ trans,
    int* __restrict__ backp, float* __restrict__ out) {
  const int b = blockIdx.x, tid = threadIdx.x;
  __shared__ float trS[KK * KK];
  __shared__ float v[KK], vn[KK];
  __shared__ float pb[200];
  __shared__ int   pi[200];
  __shared__ int   path[NT];
  __shared__ float maxsh;
  __shared__ int   zflag;
  if (tid < KK) v[tid] = emit[(size_t)(b * NT) * KK + tid];
  if (tid == 0) zflag = 0;
  __syncthreads();
  for (int t = 1; t < NT; ++t) {
    const int zf = zflag;     // uniform across block
    if (zf == 0) {
      const float* trg = trans + (size_t)(b * (NT - 1) + (t - 1)) * KK * KK;
      for (int li = tid; li < (KK * KK) / 4; li += 256)
        *(float4*)&trS[li * 4] = *(const float4*)&trg[li * 4];
      __syncthreads();
      if (tid < 200) {
        const int j = tid % 100, half = tid / 100;
        const int ia = half * 50, ibnd = ia + 50;
        float best = -FLT_MAX; int bi = ia;
        for (int i = ia; i < ibnd; ++i) {
          float s = v[i] * trS[i * KK + j];
          if (s > best) { best = s; bi = i; }     // strict > == argmax-first
        }
        pb[tid] = best; pi[tid] = bi;
      }
      __syncthreads();
      if (tid < KK) {
        float b0 = pb[tid], b1 = pb[100 + tid];
        int   i0 = pi[tid], i1 = pi[100 + tid];
        float best = b0; int bi = i0;
        if (b1 > b0) { best = b1; bi = i1; }      // half-1 indices all larger
        vn[tid] = best * emit[(size_t)(b * NT + t) * KK + tid];
        backp[(size_t)(b * (NT - 1) + (t - 1)) * KK + tid] = bi;
      }
      __syncthreads();
      if (tid == 0) {
        float m = vn[0];
        for (int j = 1; j < KK; ++j) m = fmaxf(m, vn[j]);
        maxsh = m;
        if (m == 0.0f) zflag = 1;   // exact shortcut: all-zero v is absorbing
      }
      __syncthreads();
      if (tid < KK) v[tid] = vn[tid] / fmaxf(maxsh, 1e-30f);
    } else {
      if (tid < KK) backp[(size_t)(b * (NT - 1) + (t - 1)) * KK + tid] = 0;
    }
    __syncthreads();
  }
  if (tid == 0) {
    float best = -FLT_MAX; int last = 0;
    for (int j = 0; j < KK; ++j) if (v[j] > best) { best = v[j]; last = j; }
    path[NT - 1] = last;
    for (int tt = NT - 2; tt >= 0; --tt)
      path[tt] = backp[(size_t)(b * (NT - 1) + tt) * KK + path[tt + 1]];
  }
  __syncthreads();
  for (int li = tid; li < NT * ZD; li += 256) {
    int t = li >> 7, z = li & 127;
    out[(size_t)(b * NT + t) * ZD + z] =
        T[(size_t)topi[(size_t)(b * NT + t) * KK + path[t]] * ZD + z];
  }
}

// ---------------------------------------------------------------- host
extern "C" void kernel_launch(void* const* d_in, const int* in_sizes, int n_in,
                              void* d_out, int out_size, void* d_ws, size_t ws_size,
                              hipStream_t stream) {
  const float* Q = (const float*)d_in[0];     // (4,64,128) fp32
  const float* T = (const float*)d_in[1];     // (100000,128) fp32
  float* out = (float*)d_out;                 // (4,64,128) fp32
  const int M = in_sizes[1] / ZD;
  const int slabn = (M + SLABS - 1) / SLABS;  // 391 for M=100000

  char* p = (char*)d_ws;
  auto alloc = [&](size_t bytes) -> char* {
    char* r = p; p += (bytes + 511) & ~(size_t)511; return r;
  };
  float* qn     = (float*)alloc((size_t)NQ * 4);
  float* tn     = (float*)alloc((size_t)M * 4);
  float* thr    = (float*)alloc((size_t)NQ * 4);
  int*   cnt2   = (int*)  alloc((size_t)NQ * SLABS * 4);
  int*   sure2  = (int*)  alloc((size_t)NQ * SLABS * 4);
  int*   cand   = (int*)  alloc((size_t)NQ * SLABS * BKT * 4);
  int*   topi   = (int*)  alloc((size_t)NQ * KK * 4);
  float* emit   = (float*)alloc((size_t)NQ * KK * 4);
  float* trans  = (float*)alloc((size_t)NB * (NT - 1) * KK * KK * 4);
  int*   backp  = (int*)  alloc((size_t)NB * (NT - 1) * KK * 4);

  const int g0 = (M + NQ + 255) / 256;
  k0_norms<<<g0, 256, 0, stream>>>(Q, T, M, qn, tn);
  k1_thresh<<<NQ, 256, 0, stream>>>(Q, T, M, qn, tn, thr);
  dim3 g2(SLABS, NQ / QROWS);
  k2_mfma<<<g2, 256, 0, stream>>>(Q, T, M, slabn, qn, tn, thr, cnt2, sure2, cand);
  k3_select<<<NQ, 256, 0, stream>>>(Q, T, M, qn, tn, cnt2, sure2, cand, topi, emit);
  k4_trans<<<NB * (NT - 1), 256, 0, stream>>>(T, topi, trans);
  k5_viterbi<<<NB, 256, 0, stream>>>(T, topi, emit, trans, backp, out);
}